// Round 3
// baseline (182.784 us; speedup 1.0000x reference)
//
#include <hip/hip_runtime.h>

// GRU fused, MI355X/gfx950 — round 5 (= r4 with the bit_cast compile fix).
// r3 post-mortem: occupancy 2x gave nothing (VALU-work-bound, 56% busy).
// Cuts per-step work, numerically identical to r3:
//  * OPERAND SWAP: mfma(W, h, acc) -> D is [unit][batch]. Same A/B frag
//    layouts (per-lane patterns identical), but each lane now owns 4
//    CONSECUTIVE units of one batch row -> h-write = integer RNE pack
//    + ONE ds_write_b64 (was 4x f2bf + 4x ds_write_b16).
//  * x preconverted to LDS bf16 for ALL 28 steps at init (packed stride 28
//    + guard pad; 2x ds_read_b64/step, conflict-free). Removes per-step
//    prefetch/convert/branch entirely.
//  * biases -> 16 registers (lbias/ldb LDS dropped).

#define B_  16384
#define T_  28
#define F_  28
#define H_  128
#define C_  10
#define MB  16     // batch rows per block
#define LHS 136    // lh row stride in ushorts (272 B; 2-way bank = free)
#define LXR 28     // lx row stride in ushorts (packed; b64-aligned, stride-14 dwords = conflict-free)
#define LXT (MB*LXR)   // 448 ushorts per timestep

typedef short  short8  __attribute__((ext_vector_type(8)));
typedef short  short4v __attribute__((ext_vector_type(4)));
typedef float  f32x4   __attribute__((ext_vector_type(4)));

__device__ __forceinline__ unsigned short f2bf(float f) {   // RNE fp32->bf16
    unsigned u = __builtin_bit_cast(unsigned, f);
    u += 0x7fffu + ((u >> 16) & 1u);
    return (unsigned short)(u >> 16);
}
__device__ __forceinline__ float bf2f(unsigned short h) {
    unsigned u = ((unsigned)h) << 16;
    return __builtin_bit_cast(float, u);
}
__device__ __forceinline__ float fast_sig(float x) {        // 1/(1+e^-x)
    float e = __builtin_amdgcn_exp2f(x * -1.442695040888963f);
    return __builtin_amdgcn_rcpf(1.0f + e);
}
__device__ __forceinline__ float fast_tanh(float x) {       // 1 - 2/(1+e^{2x})
    float e = __builtin_amdgcn_exp2f(x * 2.885390081777927f);
    return 1.0f - 2.0f * __builtin_amdgcn_rcpf(1.0f + e);
}

__global__ __launch_bounds__(512, 4)
void gru_fused(const float* __restrict__ x,     // (B,T,F)
               const float* __restrict__ wk,    // (F,3H) = (28,384)
               const float* __restrict__ wrk,   // (H,3H) = (128,384)
               const float* __restrict__ bias,  // (2,3H)
               const float* __restrict__ dw,    // (H,C)
               const float* __restrict__ db,    // (C,)
               float* __restrict__ out)         // (B,C)
{
    // ---- LDS (~39.6 KB) ----
    __shared__ __align__(16) unsigned short lh[2][MB*LHS];      // 8704 B, double-buffered
    __shared__ __align__(16) unsigned short lx[T_*LXT + 8];     // 25104 B (+8 ushort guard pad)
    __shared__ float ldw[H_*C_];                                // 5120 B
    __shared__ float llog[MB][C_];                              // 640 B

    const int tid  = threadIdx.x;
    const int base = blockIdx.x * MB;
    const int lane = tid & 63;
    const int wc   = tid >> 6;    // wave id 0..7 -> 16-column slice
    const int n    = lane & 15;   // A row / D col (batch)
    const int q    = lane >> 4;   // MFMA quad
    const int col  = wc*16 + n;   // weight column (A operand m-index)
    const int urow = wc*16 + q*4; // unit base this lane owns in D

    // ---- loop-invariant weight fragments -> REGISTERS (60 VGPR/wave) ----
    // frag layout (verified): elem(lane,j) = W[k = kb*32 + q*8 + j][col]
    // (identical per-lane pattern for A- and B-operand roles)
    short8 wzr[4], wrr[4], whr[4];   // W_rec per kb, gates z/r/h: 48 VGPR
    short8 xzr, xrr, xhr;            // kernel (K pad 28->32): 12 VGPR
    {
        #pragma unroll
        for (int kb = 0; kb < 4; ++kb) {
            const int k0 = kb*32 + q*8;
            short8 vz, vr, vh;
            #pragma unroll
            for (int j = 0; j < 8; ++j) {
                const float* wp = wrk + (size_t)(k0 + j)*384 + col;
                vz[j] = (short)f2bf(wp[0]);
                vr[j] = (short)f2bf(wp[128]);
                vh[j] = (short)f2bf(wp[256]);
            }
            wzr[kb] = vz; wrr[kb] = vr; whr[kb] = vh;
        }
        short8 vz, vr, vh;
        #pragma unroll
        for (int j = 0; j < 8; ++j) {
            const int k = q*8 + j;
            if (k < F_) {
                const float* wp = wk + (size_t)k*384 + col;
                vz[j] = (short)f2bf(wp[0]);
                vr[j] = (short)f2bf(wp[128]);
                vh[j] = (short)f2bf(wp[256]);
            } else { vz[j] = 0; vr[j] = 0; vh[j] = 0; }
        }
        xzr = vz; xrr = vr; xhr = vh;
    }

    // ---- biases -> registers (D rows = units, so per-lane per-reg values) ----
    float bzv[4], brv[4], bxv[4], bhv[4];
    #pragma unroll
    for (int reg = 0; reg < 4; ++reg) {
        const int u = urow + reg;
        bzv[reg] = bias[u]       + bias[384 + u];   // bi_z + br_z
        brv[reg] = bias[128 + u] + bias[512 + u];   // bi_r + br_r
        bxv[reg] = bias[256 + u];                   // bi_h
        bhv[reg] = bias[640 + u];                   // br_h
    }

    // ---- dense weights / h0 / full-x preload ----
    for (int i = tid; i < H_*C_; i += 512) ldw[i] = dw[i];
    for (int i = tid; i < MB*LHS/2; i += 512) ((unsigned*)lh[0])[i] = 0u;
    if (tid < MB*T_) {                 // 448 threads: one (row,t) each
        const int r = tid / T_;
        const int t = tid - r*T_;
        const float* xp = x + (size_t)(base + r)*(T_*F_) + t*F_;
        unsigned short* dst = &lx[t*LXT + r*LXR];
        #pragma unroll
        for (int s4 = 0; s4 < 7; ++s4) {
            float4 a = *(const float4*)(xp + s4*4);
            short4v v;
            v[0]=(short)f2bf(a.x); v[1]=(short)f2bf(a.y);
            v[2]=(short)f2bf(a.z); v[3]=(short)f2bf(a.w);
            *(short4v*)(dst + s4*4) = v;
        }
    } else if (tid == MB*T_) {         // zero the guard pad
        *(short4v*)&lx[T_*LXT]     = (short4v){0,0,0,0};
        *(short4v*)&lx[T_*LXT + 4] = (short4v){0,0,0,0};
    }

    __syncthreads();   // init visible

    float hm[4];                  // fp32 h master: units urow..urow+3, batch n
    hm[0]=0.f; hm[1]=0.f; hm[2]=0.f; hm[3]=0.f;

    const int rbase = n*LHS;      // h B-frag row base (loop-invariant)
    const int xoff  = n*LXR + q*8;

    #pragma unroll 2
    for (int t = 0; t < T_; ++t) {
        const unsigned short* __restrict__ lhr = lh[t & 1];
        unsigned short* __restrict__ lhw = lh[(t + 1) & 1];
        const unsigned short* __restrict__ lxt = lx + t*LXT;

        // B-fragments: h (4x b128) + x (2x b64; k>=28 garbage x weight-zeros)
        short8 hb[4]; short8 xbv;
        #pragma unroll
        for (int kb = 0; kb < 4; ++kb)
            hb[kb] = *(const short8*)&lhr[rbase + kb*32 + q*8];
        {
            short4v x0 = *(const short4v*)&lxt[xoff];
            short4v x1 = *(const short4v*)&lxt[xoff + 4];
            xbv = __builtin_shufflevector(x0, x1, 0,1,2,3,4,5,6,7);
        }

        f32x4 az = (f32x4){bzv[0], bzv[1], bzv[2], bzv[3]};
        f32x4 ag = (f32x4){brv[0], brv[1], brv[2], brv[3]};
        f32x4 ax = (f32x4){bxv[0], bxv[1], bxv[2], bxv[3]};
        f32x4 ah = (f32x4){bhv[0], bhv[1], bhv[2], bhv[3]};
        #pragma unroll
        for (int kb = 0; kb < 4; ++kb) {
            az = __builtin_amdgcn_mfma_f32_16x16x32_bf16(wzr[kb], hb[kb], az, 0,0,0);
            ag = __builtin_amdgcn_mfma_f32_16x16x32_bf16(wrr[kb], hb[kb], ag, 0,0,0);
            ah = __builtin_amdgcn_mfma_f32_16x16x32_bf16(whr[kb], hb[kb], ah, 0,0,0);
        }
        az = __builtin_amdgcn_mfma_f32_16x16x32_bf16(xzr, xbv, az, 0,0,0);
        ag = __builtin_amdgcn_mfma_f32_16x16x32_bf16(xrr, xbv, ag, 0,0,0);
        ax = __builtin_amdgcn_mfma_f32_16x16x32_bf16(xhr, xbv, ax, 0,0,0);

        // gates + h update; D layout: row = q*4+reg (unit), col = n (batch)
        float hn[4];
        #pragma unroll
        for (int reg = 0; reg < 4; ++reg) {
            float z  = fast_sig(az[reg]);
            float r  = fast_sig(ag[reg]);
            float hh = fast_tanh(ax[reg] + r * ah[reg]);
            float hv = hh + z * (hm[reg] - hh);
            hm[reg] = hv; hn[reg] = hv;
        }
        // packed write: 4 consecutive units of batch row n -> one ds_write_b64
        uint2 pk;
        pk.x = ((unsigned)f2bf(hn[1]) << 16) | (unsigned)f2bf(hn[0]);
        pk.y = ((unsigned)f2bf(hn[3]) << 16) | (unsigned)f2bf(hn[2]);
        *(uint2*)&lhw[n*LHS + urow] = pk;

        __syncthreads();   // h_{t+1} published
    }

    // ---- dense + softmax epilogue (final h in lh[0]: last write t=27 -> (27+1)&1) ----
    if (tid < MB*C_) {
        const int row = tid / C_, c = tid - row*C_;
        float s = db[c];
        #pragma unroll
        for (int u0 = 0; u0 < H_; u0 += 8) {
            short8 hv = *(const short8*)&lh[0][row*LHS + u0];
            #pragma unroll
            for (int j = 0; j < 8; ++j)
                s += bf2f((unsigned short)hv[j]) * ldw[(u0+j)*C_ + c];
        }
        llog[row][c] = s;
    }
    __syncthreads();
    if (tid < MB) {
        const int row = tid;
        float m = llog[row][0];
        #pragma unroll
        for (int c = 1; c < C_; ++c) m = fmaxf(m, llog[row][c]);
        float e[C_], s = 0.f;
        #pragma unroll
        for (int c = 0; c < C_; ++c) {
            e[c] = __builtin_amdgcn_exp2f((llog[row][c] - m) * 1.442695040888963f);
            s += e[c];
        }
        const float inv = __builtin_amdgcn_rcpf(s);
        float* o = out + (size_t)(base + row)*C_;
        #pragma unroll
        for (int c = 0; c < C_; ++c) o[c] = e[c] * inv;
    }
}

extern "C" void kernel_launch(void* const* d_in, const int* in_sizes, int n_in,
                              void* d_out, int out_size, void* d_ws, size_t ws_size,
                              hipStream_t stream) {
    const float* x   = (const float*)d_in[0];
    const float* wk  = (const float*)d_in[1];
    const float* wrk = (const float*)d_in[2];
    const float* bs  = (const float*)d_in[3];
    const float* dw  = (const float*)d_in[4];
    const float* db  = (const float*)d_in[5];
    (void)in_sizes; (void)n_in; (void)out_size; (void)d_ws; (void)ws_size;
    gru_fused<<<dim3(B_/MB), dim3(512), 0, stream>>>(x, wk, wrk, bs, dw, db, (float*)d_out);
}